// Round 1
// baseline (221.035 us; speedup 1.0000x reference)
//
#include <hip/hip_runtime.h>
#include <hip/hip_bf16.h>
#include <math.h>

#define NB 512
#define NS 200
#define NH 256
#define TILE_S 32
#define LDSPAD 8
#define LDW (NH + LDSPAD)        // 264 f16 row stride: 528B rows -> 2-way bank aliasing only (free)
#define WS_STRIDE 258            // per (b,half): [m, Z, pooled[256]]
#define NPART (NB * 2)           // 1024 partial blocks

// ws float-offset layout
#define OFF_PART 0
#define OFF_L    (NPART * WS_STRIDE)              // partials: 1024*258 floats
#define OFF_UB   (OFF_L + NB * NH)                // l: 512*256 floats
#define WS_FLOATS_PRE  (OFF_UB + (NH * NH) / 2)   // + U-fp16 swizzled (32768 floats) = 1.71 MB

typedef _Float16 f16x8 __attribute__((ext_vector_type(8)));
typedef float    f32x4 __attribute__((ext_vector_type(4)));

__device__ __forceinline__ float tanh_fast(float x) {
  float xc = fminf(fmaxf(x, -10.f), 10.f);
  float e  = __expf(2.f * xc);
  return (e - 1.f) / (e + 1.f);
}

// ---------------- Kernel 0: precompute l = lastm@W^T (fp32) and swizzled fp16 U ----
// Uswz frag id = ((n_blk*8 + kk)*64 + lane), 8 f16 each:
// contents U[n_blk*16 + (lane&15)][kk*32 + (lane>>4)*8 + j], j=0..7
__global__ __launch_bounds__(256)
void precompute(const float* __restrict__ lastm, const float* __restrict__ W,
                const float* __restrict__ U,
                float* __restrict__ l_ws, _Float16* __restrict__ Uswz)
{
  const int t = threadIdx.x;
  if (blockIdx.x < NB) {
    const int b = blockIdx.x;
    __shared__ float lm_sm[NH];
    lm_sm[t] = lastm[(size_t)b * NH + t];
    __syncthreads();
    const float4* wrow = (const float4*)(W + (size_t)t * NH);
    const float4* lrow = (const float4*)lm_sm;
    float a0 = 0.f, a1 = 0.f, a2 = 0.f, a3 = 0.f;
#pragma unroll 8
    for (int i = 0; i < NH / 4; ++i) {
      float4 w4 = wrow[i];
      float4 m4 = lrow[i];
      a0 = fmaf(w4.x, m4.x, a0);
      a1 = fmaf(w4.y, m4.y, a1);
      a2 = fmaf(w4.z, m4.z, a2);
      a3 = fmaf(w4.w, m4.w, a3);
    }
    l_ws[(size_t)b * NH + t] = (a0 + a1) + (a2 + a3);
  } else {
    const int id    = (blockIdx.x - NB) * 256 + t;   // 8192 frags
    const int n_blk = id >> 9;
    const int kk    = (id >> 6) & 7;
    const int lane  = id & 63;
    const int row   = n_blk * 16 + (lane & 15);
    const int col   = kk * 32 + (lane >> 4) * 8;
    const float4* s = (const float4*)(U + (size_t)row * NH + col);
    const float4 a = s[0], c = s[1];
    f16x8 pk;
    pk[0] = (_Float16)a.x; pk[1] = (_Float16)a.y;
    pk[2] = (_Float16)a.z; pk[3] = (_Float16)a.w;
    pk[4] = (_Float16)c.x; pk[5] = (_Float16)c.y;
    pk[6] = (_Float16)c.z; pk[7] = (_Float16)c.w;
    *(f16x8*)(Uswz + (size_t)id * 8) = pk;
  }
}

// ---------------- Kernel 1: partial attention over an S-range ----------------
// grid = 1024: block (b, half). half 0 -> s in [0,96), half 1 -> s in [96,200).
// __launch_bounds__(256,2): R1-proven codegen (u_frag in regs, NO scratch spill).
// Do NOT request min 4 waves/EU (R2-R4: spills accumulators, 94 MB scratch traffic).
// Precision: mem staged as fp16 (hi,lo) pair -> scores exact to ~2^-17 in mem and
// ~2^-11 in U (fp16), vs bf16's 2^-9/2^-9 which sat AT the harness threshold.
template<bool PRE>
__global__ __launch_bounds__(256, 2)
void fused_meta_attn_part(const float* __restrict__ mem,    // [B,S,H]
                          const float* __restrict__ lastm,  // [B,H]
                          const float* __restrict__ U,      // [H,H] fp32 (fallback)
                          const float* __restrict__ W,      // [H,H] (fallback)
                          const float* __restrict__ V,      // [H]
                          const float* __restrict__ l_ws,   // [B,H] (PRE)
                          const _Float16* __restrict__ Uswz,// swizzled fp16 U (PRE)
                          float* __restrict__ part)         // [NPART, WS_STRIDE]
{
  const int b    = blockIdx.x >> 1;
  const int half = blockIdx.x & 1;
  const int s_begin = half ? 96 : 0;
  const int s_end   = half ? NS : 96;
  const int ntiles  = half ? 4 : 3;

  const int t    = threadIdx.x;   // 0..255
  const int wave = t >> 6;        // owns n-cols [wave*64, wave*64+64)
  const int lane = t & 63;
  const int m16  = lane & 15;
  const int quad = lane >> 4;

  __shared__ __align__(16) _Float16 hi_sm[TILE_S][LDW];  // 16.9 KB
  __shared__ __align__(16) _Float16 lo_sm[TILE_S][LDW];  // 16.9 KB
  __shared__ float swave_sm[4][TILE_S];
  __shared__ float scores_sm[TILE_S];
  __shared__ float l_sm[NH];      // fallback only
  __shared__ float lm_sm[NH];     // fallback only

  if (!PRE) {
    lm_sm[t] = lastm[(size_t)b * NH + t];
    __syncthreads();
    const float4* wrow = (const float4*)(W + (size_t)t * NH);
    const float4* lrow = (const float4*)lm_sm;
    float a0 = 0.f, a1 = 0.f, a2 = 0.f, a3 = 0.f;
#pragma unroll 8
    for (int i = 0; i < NH / 4; ++i) {
      float4 w4 = wrow[i];
      float4 m4 = lrow[i];
      a0 = fmaf(w4.x, m4.x, a0);
      a1 = fmaf(w4.y, m4.y, a1);
      a2 = fmaf(w4.z, m4.z, a2);
      a3 = fmaf(w4.w, m4.w, a3);
    }
    l_sm[t] = (a0 + a1) + (a2 + a3);
    __syncthreads();
  }

  // per-thread l/V for this wave's 4 n-fragments
  float l_reg[4], v_reg[4];
#pragma unroll
  for (int nf = 0; nf < 4; ++nf) {
    const int n = wave * 64 + nf * 16 + m16;
    l_reg[nf] = PRE ? l_ws[(size_t)b * NH + n] : l_sm[n];
    v_reg[nf] = V[n];
  }

  // ---- U B-fragments into registers, held for the whole kernel (R1-style) ----
  f16x8 u_frag[4][8];
  if (PRE) {
    // linear per-wave reads: frag id = ((wave*4+nf)*8 + kk)*64 + lane
    const _Float16* uw = Uswz + ((size_t)(wave * 4 * 8 * 64) + lane) * 8;
#pragma unroll
    for (int nf = 0; nf < 4; ++nf)
#pragma unroll
      for (int kk = 0; kk < 8; ++kk)
        u_frag[nf][kk] = *(const f16x8*)(uw + (size_t)((nf * 8 + kk) << 9));
  } else {
#pragma unroll
    for (int nf = 0; nf < 4; ++nf) {
      const int n = wave * 64 + nf * 16 + m16;
      const float* urow = U + (size_t)n * NH;
#pragma unroll
      for (int kk = 0; kk < 8; ++kk) {
        const float4 lo = *(const float4*)(urow + kk * 32 + quad * 8);
        const float4 hi = *(const float4*)(urow + kk * 32 + quad * 8 + 4);
        f16x8 f;
        f[0] = (_Float16)lo.x; f[1] = (_Float16)lo.y;
        f[2] = (_Float16)lo.z; f[3] = (_Float16)lo.w;
        f[4] = (_Float16)hi.x; f[5] = (_Float16)hi.y;
        f[6] = (_Float16)hi.z; f[7] = (_Float16)hi.w;
        u_frag[nf][kk] = f;
      }
    }
  }

  float m_run  = -INFINITY;
  float Z      = 0.f;
  float pooled = 0.f;   // thread t owns h = t (unnormalized, relative to m_run)

  for (int tile = 0; tile < ntiles; ++tile) {
    const int s0   = s_begin + tile * TILE_S;
    const int rows = min(TILE_S, s_end - s0);

    // ---- stage fp32 -> fp16 hi/lo LDS (regular cached loads: mem stays L3-warm) ----
    const float4* src4 = (const float4*)(mem + ((size_t)b * NS + s0) * NH);
#pragma unroll
    for (int i = 0; i < 4; ++i) {
      const int f2  = i * 256 + t;
      const int row = f2 >> 5;
      const int c8  = (f2 & 31) * 8;
      f16x8 ph, pl;
      if (row < rows) {
        const float4 a = src4[f2 * 2];
        const float4 c = src4[f2 * 2 + 1];
#define CVT_HL(idx, val) { const float x_ = (val); const _Float16 h_ = (_Float16)x_; \
                           ph[idx] = h_; pl[idx] = (_Float16)(x_ - (float)h_); }
        CVT_HL(0, a.x) CVT_HL(1, a.y) CVT_HL(2, a.z) CVT_HL(3, a.w)
        CVT_HL(4, c.x) CVT_HL(5, c.y) CVT_HL(6, c.z) CVT_HL(7, c.w)
#undef CVT_HL
      } else {
        ph = (f16x8)(_Float16)0.f;
        pl = (f16x8)(_Float16)0.f;
      }
      *(f16x8*)&hi_sm[row][c8] = ph;
      *(f16x8*)&lo_sm[row][c8] = pl;
    }
    __syncthreads();

    // ---- MFMA: a[s,n] 32 rows x 64 cols per wave; hi+lo both into same acc ----
    f32x4 acc[2][4];
    const f32x4 fzero = {0.f, 0.f, 0.f, 0.f};
#pragma unroll
    for (int mt = 0; mt < 2; ++mt)
#pragma unroll
      for (int nf = 0; nf < 4; ++nf)
        acc[mt][nf] = fzero;

#pragma unroll
    for (int kk = 0; kk < 8; ++kk) {
      const int c = kk * 32 + quad * 8;
      f16x8 a0h = *(const f16x8*)&hi_sm[m16][c];
      f16x8 a1h = *(const f16x8*)&hi_sm[16 + m16][c];
      f16x8 a0l = *(const f16x8*)&lo_sm[m16][c];
      f16x8 a1l = *(const f16x8*)&lo_sm[16 + m16][c];
#pragma unroll
      for (int nf = 0; nf < 4; ++nf) {
        acc[0][nf] = __builtin_amdgcn_mfma_f32_16x16x32_f16(a0h, u_frag[nf][kk], acc[0][nf], 0, 0, 0);
        acc[1][nf] = __builtin_amdgcn_mfma_f32_16x16x32_f16(a1h, u_frag[nf][kk], acc[1][nf], 0, 0, 0);
        acc[0][nf] = __builtin_amdgcn_mfma_f32_16x16x32_f16(a0l, u_frag[nf][kk], acc[0][nf], 0, 0, 0);
        acc[1][nf] = __builtin_amdgcn_mfma_f32_16x16x32_f16(a1l, u_frag[nf][kk], acc[1][nf], 0, 0, 0);
      }
    }

    // ---- p = sum_n tanh(a + l[n]) * V[n] over this wave's 64 n ----
    float p[2][4];
#pragma unroll
    for (int mt = 0; mt < 2; ++mt) {
#pragma unroll
      for (int reg = 0; reg < 4; ++reg) {
        float s = 0.f;
#pragma unroll
        for (int nf = 0; nf < 4; ++nf)
          s = fmaf(tanh_fast(acc[mt][nf][reg] + l_reg[nf]), v_reg[nf], s);
        p[mt][reg] = s;
      }
    }
#pragma unroll
    for (int off = 1; off < 16; off <<= 1) {
#pragma unroll
      for (int mt = 0; mt < 2; ++mt)
#pragma unroll
        for (int reg = 0; reg < 4; ++reg)
          p[mt][reg] += __shfl_xor(p[mt][reg], off);
    }
    if (m16 == 0) {
#pragma unroll
      for (int mt = 0; mt < 2; ++mt)
#pragma unroll
        for (int reg = 0; reg < 4; ++reg)
          swave_sm[wave][mt * 16 + quad * 4 + reg] = p[mt][reg];
    }
    __syncthreads();

    if (t < TILE_S)
      scores_sm[t] = swave_sm[0][t] + swave_sm[1][t] + swave_sm[2][t] + swave_sm[3][t];
    __syncthreads();

    // ---- online softmax + pooled update (all threads compute identical m/Z) ----
    float m_tile = -INFINITY;
    for (int r = 0; r < rows; ++r) m_tile = fmaxf(m_tile, scores_sm[r]);
    const float m_new = fmaxf(m_run, m_tile);
    const float fac   = __expf(m_run - m_new);
    float z_t = 0.f, pool_t = 0.f;
    for (int r = 0; r < rows; ++r) {
      const float e = __expf(scores_sm[r] - m_new);
      z_t += e;
      pool_t = fmaf(e, (float)hi_sm[r][t] + (float)lo_sm[r][t], pool_t);
    }
    Z      = Z * fac + z_t;
    pooled = pooled * fac + pool_t;
    m_run  = m_new;
    __syncthreads();
  }

  float* base = part + (size_t)blockIdx.x * WS_STRIDE;
  if (t == 0) { base[0] = m_run; base[1] = Z; }
  base[2 + t] = pooled;
}

// ---------------- Kernel 2: merge halves + MetaW projection ----------------
__global__ __launch_bounds__(256)
void merge_project(const float* __restrict__ part,
                   const float* __restrict__ MetaW,  // [4,H]
                   const float* __restrict__ Metab,  // [4]
                   float* __restrict__ out)          // [B,4]
{
  const int b    = blockIdx.x;
  const int t    = threadIdx.x;
  const int wave = t >> 6;
  const int lane = t & 63;

  __shared__ float pooled_sm[NH];

  const float* b0 = part + (size_t)(b * 2)     * WS_STRIDE;
  const float* b1 = part + (size_t)(b * 2 + 1) * WS_STRIDE;
  const float m0 = b0[0], Z0 = b0[1];
  const float m1 = b1[0], Z1 = b1[1];
  const float mm = fmaxf(m0, m1);
  const float w0 = __expf(m0 - mm);
  const float w1 = __expf(m1 - mm);
  const float Zi = 1.f / (Z0 * w0 + Z1 * w1);

  pooled_sm[t] = (b0[2 + t] * w0 + b1[2 + t] * w1) * Zi;
  __syncthreads();

  float s = 0.f;
#pragma unroll
  for (int i = 0; i < 4; ++i) {
    const int h = i * 64 + lane;
    s = fmaf(pooled_sm[h], MetaW[(size_t)wave * NH + h], s);
  }
#pragma unroll
  for (int off = 32; off > 0; off >>= 1)
    s += __shfl_down(s, off);
  if (lane == 0)
    out[b * 4 + wave] = s + Metab[wave];
}

extern "C" void kernel_launch(void* const* d_in, const int* in_sizes, int n_in,
                              void* d_out, int out_size, void* d_ws, size_t ws_size,
                              hipStream_t stream) {
  const float* mem   = (const float*)d_in[0];
  const float* lastm = (const float*)d_in[1];
  const float* U     = (const float*)d_in[2];
  const float* W     = (const float*)d_in[3];
  const float* V     = (const float*)d_in[4];
  const float* MetaW = (const float*)d_in[5];
  const float* Metab = (const float*)d_in[6];
  float* out = (float*)d_out;
  float* ws  = (float*)d_ws;

  float* part = ws + OFF_PART;

  if (ws_size >= (size_t)WS_FLOATS_PRE * sizeof(float)) {
    float*    l_ws = ws + OFF_L;
    _Float16* Uswz = (_Float16*)(ws + OFF_UB);
    hipLaunchKernelGGL(precompute, dim3(NB + 32), dim3(256), 0, stream,
                       lastm, W, U, l_ws, Uswz);
    hipLaunchKernelGGL(fused_meta_attn_part<true>, dim3(NPART), dim3(256), 0, stream,
                       mem, lastm, U, W, V, l_ws, Uswz, part);
  } else {
    hipLaunchKernelGGL(fused_meta_attn_part<false>, dim3(NPART), dim3(256), 0, stream,
                       mem, lastm, U, W, V, (const float*)nullptr, (const _Float16*)nullptr, part);
  }
  hipLaunchKernelGGL(merge_project, dim3(NB), dim3(256), 0, stream,
                     part, MetaW, Metab, out);
}

// Round 2
// 210.824 us; speedup vs baseline: 1.0484x; 1.0484x over previous
//
#include <hip/hip_runtime.h>
#include <hip/hip_bf16.h>
#include <math.h>

#define NB 512
#define NS 200
#define NH 256
#define TILE_S 32
#define LDSPAD 8
#define LDW (NH + LDSPAD)        // 264 f16 row stride: 528B rows -> 4-bank row step, conflict-free b128
#define WS_STRIDE 258            // per (b,half): [m, Z, pooled[256]]
#define NPART (NB * 2)           // 1024 partial blocks

// ws float-offset layout
#define OFF_PART 0
#define OFF_L    (NPART * WS_STRIDE)              // partials: 1024*258 floats
#define OFF_UB   (OFF_L + NB * NH)                // l: 512*256 floats
#define WS_FLOATS_PRE  (OFF_UB + (NH * NH) / 2)   // + U-fp16 swizzled (32768 floats) = 1.71 MB

typedef _Float16 f16x8 __attribute__((ext_vector_type(8)));
typedef float    f32x4 __attribute__((ext_vector_type(4)));

// ---------------- Kernel 0: precompute l = lastm@W^T (fp32) and swizzled fp16 U ----
// Uswz frag id = ((n_blk*8 + kk)*64 + lane), 8 f16 each:
// contents U[n_blk*16 + (lane&15)][kk*32 + (lane>>4)*8 + j], j=0..7
__global__ __launch_bounds__(256)
void precompute(const float* __restrict__ lastm, const float* __restrict__ W,
                const float* __restrict__ U,
                float* __restrict__ l_ws, _Float16* __restrict__ Uswz)
{
  const int t = threadIdx.x;
  if (blockIdx.x < NB) {
    const int b = blockIdx.x;
    __shared__ float lm_sm[NH];
    lm_sm[t] = lastm[(size_t)b * NH + t];
    __syncthreads();
    const float4* wrow = (const float4*)(W + (size_t)t * NH);
    const float4* lrow = (const float4*)lm_sm;
    float a0 = 0.f, a1 = 0.f, a2 = 0.f, a3 = 0.f;
#pragma unroll 8
    for (int i = 0; i < NH / 4; ++i) {
      float4 w4 = wrow[i];
      float4 m4 = lrow[i];
      a0 = fmaf(w4.x, m4.x, a0);
      a1 = fmaf(w4.y, m4.y, a1);
      a2 = fmaf(w4.z, m4.z, a2);
      a3 = fmaf(w4.w, m4.w, a3);
    }
    l_ws[(size_t)b * NH + t] = (a0 + a1) + (a2 + a3);
  } else {
    const int id    = (blockIdx.x - NB) * 256 + t;   // 8192 frags
    const int n_blk = id >> 9;
    const int kk    = (id >> 6) & 7;
    const int lane  = id & 63;
    const int row   = n_blk * 16 + (lane & 15);
    const int col   = kk * 32 + (lane >> 4) * 8;
    const float4* s = (const float4*)(U + (size_t)row * NH + col);
    const float4 a = s[0], c = s[1];
    f16x8 pk;
    pk[0] = (_Float16)a.x; pk[1] = (_Float16)a.y;
    pk[2] = (_Float16)a.z; pk[3] = (_Float16)a.w;
    pk[4] = (_Float16)c.x; pk[5] = (_Float16)c.y;
    pk[6] = (_Float16)c.z; pk[7] = (_Float16)c.w;
    *(f16x8*)(Uswz + (size_t)id * 8) = pk;
  }
}

// ---------------- Kernel 1: partial attention over an S-range ----------------
// grid = 1024: block (b, half). half 0 -> s in [0,96), half 1 -> s in [96,200).
// 512 threads = 8 waves, each wave owns 32 n-cols -> u_frag[2][8] = 64 VGPR
// (vs 128 for the 4-wave/64-col split, which silently capped occupancy at
// 2 waves/EU via the unified VGPR+AGPR file). __launch_bounds__(512,4):
// 4 waves/EU = 16 waves/CU = 2 blocks/CU, VGPR cap 128.
// Precision: mem staged as fp16 (hi,lo) pair for MFMA scores (~2^-17);
// pooled pass reads hi only (2^-11) -> adds ~2e-4 output error vs 6.4e-3 thr.
template<bool PRE>
__global__ __launch_bounds__(512, 4)
void fused_meta_attn_part(const float* __restrict__ mem,    // [B,S,H]
                          const float* __restrict__ lastm,  // [B,H]
                          const float* __restrict__ U,      // [H,H] fp32 (fallback)
                          const float* __restrict__ W,      // [H,H] (fallback)
                          const float* __restrict__ V,      // [H]
                          const float* __restrict__ l_ws,   // [B,H] (PRE)
                          const _Float16* __restrict__ Uswz,// swizzled fp16 U (PRE)
                          float* __restrict__ part)         // [NPART, WS_STRIDE]
{
  const int b    = blockIdx.x >> 1;
  const int half = blockIdx.x & 1;
  const int s_begin = half ? 96 : 0;
  const int s_end   = half ? NS : 96;
  const int ntiles  = half ? 4 : 3;

  const int t     = threadIdx.x;   // 0..511
  const int wave  = t >> 6;        // 0..7: owns n-cols [wave*32, wave*32+32)
  const int lane  = t & 63;
  const int m16   = lane & 15;
  const int quad  = lane >> 4;
  const int hcol  = t & 255;       // pooled: h column this thread owns
  const int rhalf = t >> 8;        // pooled: 0 -> rows 0..15, 1 -> rows 16..31

  __shared__ __align__(16) _Float16 hi_sm[TILE_S][LDW];  // 16.9 KB
  __shared__ __align__(16) _Float16 lo_sm[TILE_S][LDW];  // 16.9 KB
  __shared__ float swave_sm[8][TILE_S];                  // also reused as final scratch
  __shared__ __align__(16) float e_sm[TILE_S];
  __shared__ float mz_sm[2];
  __shared__ float l_sm[NH];      // fallback only (eliminated in PRE=true)
  __shared__ float lm_sm[NH];     // fallback only

  if (!PRE) {
    if (t < NH) lm_sm[t] = lastm[(size_t)b * NH + t];
    __syncthreads();
    if (t < NH) {
      const float4* wrow = (const float4*)(W + (size_t)t * NH);
      const float4* lrow = (const float4*)lm_sm;
      float a0 = 0.f, a1 = 0.f, a2 = 0.f, a3 = 0.f;
#pragma unroll 8
      for (int i = 0; i < NH / 4; ++i) {
        float4 w4 = wrow[i];
        float4 m4 = lrow[i];
        a0 = fmaf(w4.x, m4.x, a0);
        a1 = fmaf(w4.y, m4.y, a1);
        a2 = fmaf(w4.z, m4.z, a2);
        a3 = fmaf(w4.w, m4.w, a3);
      }
      l_sm[t] = (a0 + a1) + (a2 + a3);
    }
    __syncthreads();
  }

  // per-thread l/V for this wave's 2 n-fragments
  float l_reg[2], v_reg[2];
#pragma unroll
  for (int nf = 0; nf < 2; ++nf) {
    const int n = wave * 32 + nf * 16 + m16;
    l_reg[nf] = PRE ? l_ws[(size_t)b * NH + n] : l_sm[n];
    v_reg[nf] = V[n];
  }
  const float vsum  = v_reg[0] + v_reg[1];
  const float vm2_0 = -2.f * v_reg[0];
  const float vm2_1 = -2.f * v_reg[1];

  // ---- U B-fragments in registers for the whole kernel: 2 nf x 8 kk = 64 VGPR ----
  f16x8 u_frag[2][8];
  if (PRE) {
    // frag id = ((wave*2 + nf)*8 + kk)*64 + lane  -> linear per wave
    const _Float16* uw = Uswz + ((size_t)(wave * 2 * 8 * 64) + lane) * 8;
#pragma unroll
    for (int nf = 0; nf < 2; ++nf)
#pragma unroll
      for (int kk = 0; kk < 8; ++kk)
        u_frag[nf][kk] = *(const f16x8*)(uw + (size_t)((nf * 8 + kk) << 9));
  } else {
#pragma unroll
    for (int nf = 0; nf < 2; ++nf) {
      const int n = wave * 32 + nf * 16 + m16;
      const float* urow = U + (size_t)n * NH;
#pragma unroll
      for (int kk = 0; kk < 8; ++kk) {
        const float4 lo = *(const float4*)(urow + kk * 32 + quad * 8);
        const float4 hi = *(const float4*)(urow + kk * 32 + quad * 8 + 4);
        f16x8 f;
        f[0] = (_Float16)lo.x; f[1] = (_Float16)lo.y;
        f[2] = (_Float16)lo.z; f[3] = (_Float16)lo.w;
        f[4] = (_Float16)hi.x; f[5] = (_Float16)hi.y;
        f[6] = (_Float16)hi.z; f[7] = (_Float16)hi.w;
        u_frag[nf][kk] = f;
      }
    }
  }

  float m_run  = -INFINITY;
  float Z      = 0.f;
  float pooled = 0.f;   // thread owns h = hcol, rows-half rhalf (unnormalized)

  for (int tile = 0; tile < ntiles; ++tile) {
    const int s0   = s_begin + tile * TILE_S;
    const int rows = min(TILE_S, s_end - s0);

    // ---- stage fp32 -> fp16 hi/lo LDS: 16 elems/thread ----
    const float4* src4 = (const float4*)(mem + ((size_t)b * NS + s0) * NH);
#pragma unroll
    for (int i = 0; i < 2; ++i) {
      const int f2  = i * 512 + t;
      const int row = f2 >> 5;
      const int c8  = (f2 & 31) * 8;
      f16x8 ph, pl;
      if (row < rows) {
        const float4 a = src4[f2 * 2];
        const float4 c = src4[f2 * 2 + 1];
#define CVT_HL(idx, val) { const float x_ = (val); const _Float16 h_ = (_Float16)x_; \
                           ph[idx] = h_; pl[idx] = (_Float16)(x_ - (float)h_); }
        CVT_HL(0, a.x) CVT_HL(1, a.y) CVT_HL(2, a.z) CVT_HL(3, a.w)
        CVT_HL(4, c.x) CVT_HL(5, c.y) CVT_HL(6, c.z) CVT_HL(7, c.w)
#undef CVT_HL
      } else {
        ph = (f16x8)(_Float16)0.f;
        pl = (f16x8)(_Float16)0.f;
      }
      *(f16x8*)&hi_sm[row][c8] = ph;
      *(f16x8*)&lo_sm[row][c8] = pl;
    }
    __syncthreads();

    // ---- MFMA: 32 rows x 32 n-cols per wave; hi+lo into same acc ----
    f32x4 acc[2][2];
    const f32x4 fzero = {0.f, 0.f, 0.f, 0.f};
#pragma unroll
    for (int mt = 0; mt < 2; ++mt)
#pragma unroll
      for (int nf = 0; nf < 2; ++nf)
        acc[mt][nf] = fzero;

#pragma unroll
    for (int kk = 0; kk < 8; ++kk) {
      const int c = kk * 32 + quad * 8;
      f16x8 a0h = *(const f16x8*)&hi_sm[m16][c];
      f16x8 a1h = *(const f16x8*)&hi_sm[16 + m16][c];
      f16x8 a0l = *(const f16x8*)&lo_sm[m16][c];
      f16x8 a1l = *(const f16x8*)&lo_sm[16 + m16][c];
#pragma unroll
      for (int nf = 0; nf < 2; ++nf) {
        acc[0][nf] = __builtin_amdgcn_mfma_f32_16x16x32_f16(a0h, u_frag[nf][kk], acc[0][nf], 0, 0, 0);
        acc[1][nf] = __builtin_amdgcn_mfma_f32_16x16x32_f16(a1h, u_frag[nf][kk], acc[1][nf], 0, 0, 0);
        acc[0][nf] = __builtin_amdgcn_mfma_f32_16x16x32_f16(a0l, u_frag[nf][kk], acc[0][nf], 0, 0, 0);
        acc[1][nf] = __builtin_amdgcn_mfma_f32_16x16x32_f16(a1l, u_frag[nf][kk], acc[1][nf], 0, 0, 0);
      }
    }

    // ---- p = sum_n v[n]*tanh(a+l[n]) via tanh(x) = 1 - 2/(e^{2x}+1):
    //      p = vsum + sum_nf (-2 v[nf]) / (e^{2x}+1). Saturates correctly at +-inf.
    float p[2][4];
#pragma unroll
    for (int mt = 0; mt < 2; ++mt) {
#pragma unroll
      for (int reg = 0; reg < 4; ++reg) {
        const float x0 = acc[mt][0][reg] + l_reg[0];
        const float x1 = acc[mt][1][reg] + l_reg[1];
        const float e0 = __expf(x0 + x0);
        const float e1 = __expf(x1 + x1);
        float s = vsum;
        s += __fdividef(vm2_0, e0 + 1.f);
        s += __fdividef(vm2_1, e1 + 1.f);
        p[mt][reg] = s;
      }
    }
#pragma unroll
    for (int off = 1; off < 16; off <<= 1) {
#pragma unroll
      for (int mt = 0; mt < 2; ++mt)
#pragma unroll
        for (int reg = 0; reg < 4; ++reg)
          p[mt][reg] += __shfl_xor(p[mt][reg], off);
    }
    if (m16 == 0) {
#pragma unroll
      for (int mt = 0; mt < 2; ++mt)
#pragma unroll
        for (int reg = 0; reg < 4; ++reg)
          swave_sm[wave][mt * 16 + quad * 4 + reg] = p[mt][reg];
    }
    __syncthreads();

    // ---- wave0 lanes 0..31: scores, tile max, e[], z (once, not per-thread) ----
    if (t < TILE_S) {
      float s = swave_sm[0][t];
#pragma unroll
      for (int w = 1; w < 8; ++w) s += swave_sm[w][t];
      const float sv = (t < rows) ? s : -INFINITY;
      float mt_ = sv;
#pragma unroll
      for (int off = 1; off < 32; off <<= 1)
        mt_ = fmaxf(mt_, __shfl_xor(mt_, off));
      const float m_new = fmaxf(m_run, mt_);
      float e = (t < rows) ? __expf(sv - m_new) : 0.f;
      e_sm[t] = e;
      float z = e;
#pragma unroll
      for (int off = 1; off < 32; off <<= 1)
        z += __shfl_xor(z, off);
      if (t == 0) { mz_sm[0] = m_new; mz_sm[1] = z; }
    }
    __syncthreads();

    // ---- all threads: rescale + 16-row pooled FMA (e preloaded as 4x b128) ----
    const float m_new = mz_sm[0];
    const float z_new = mz_sm[1];
    const float fac   = __expf(m_run - m_new);
    m_run = m_new;
    Z = fmaf(Z, fac, z_new);

    const int r0 = rhalf * 16;
    const float4 ev0 = *(const float4*)&e_sm[r0 + 0];
    const float4 ev1 = *(const float4*)&e_sm[r0 + 4];
    const float4 ev2 = *(const float4*)&e_sm[r0 + 8];
    const float4 ev3 = *(const float4*)&e_sm[r0 + 12];
    float pt = 0.f;
    pt = fmaf(ev0.x, (float)hi_sm[r0 +  0][hcol], pt);
    pt = fmaf(ev0.y, (float)hi_sm[r0 +  1][hcol], pt);
    pt = fmaf(ev0.z, (float)hi_sm[r0 +  2][hcol], pt);
    pt = fmaf(ev0.w, (float)hi_sm[r0 +  3][hcol], pt);
    pt = fmaf(ev1.x, (float)hi_sm[r0 +  4][hcol], pt);
    pt = fmaf(ev1.y, (float)hi_sm[r0 +  5][hcol], pt);
    pt = fmaf(ev1.z, (float)hi_sm[r0 +  6][hcol], pt);
    pt = fmaf(ev1.w, (float)hi_sm[r0 +  7][hcol], pt);
    pt = fmaf(ev2.x, (float)hi_sm[r0 +  8][hcol], pt);
    pt = fmaf(ev2.y, (float)hi_sm[r0 +  9][hcol], pt);
    pt = fmaf(ev2.z, (float)hi_sm[r0 + 10][hcol], pt);
    pt = fmaf(ev2.w, (float)hi_sm[r0 + 11][hcol], pt);
    pt = fmaf(ev3.x, (float)hi_sm[r0 + 12][hcol], pt);
    pt = fmaf(ev3.y, (float)hi_sm[r0 + 13][hcol], pt);
    pt = fmaf(ev3.z, (float)hi_sm[r0 + 14][hcol], pt);
    pt = fmaf(ev3.w, (float)hi_sm[r0 + 15][hcol], pt);
    pooled = fmaf(pooled, fac, pt);
    __syncthreads();
  }

  // ---- combine row-halves (reuse swave_sm as 256-float scratch) + write part ----
  float* scratch = &swave_sm[0][0];
  if (rhalf == 1) scratch[hcol] = pooled;
  __syncthreads();
  float* base = part + (size_t)blockIdx.x * WS_STRIDE;
  if (t == 0) { base[0] = m_run; base[1] = Z; }
  if (rhalf == 0) base[2 + hcol] = pooled + scratch[hcol];
}

// ---------------- Kernel 2: merge halves + MetaW projection ----------------
__global__ __launch_bounds__(256)
void merge_project(const float* __restrict__ part,
                   const float* __restrict__ MetaW,  // [4,H]
                   const float* __restrict__ Metab,  // [4]
                   float* __restrict__ out)          // [B,4]
{
  const int b    = blockIdx.x;
  const int t    = threadIdx.x;
  const int wave = t >> 6;
  const int lane = t & 63;

  __shared__ float pooled_sm[NH];

  const float* b0 = part + (size_t)(b * 2)     * WS_STRIDE;
  const float* b1 = part + (size_t)(b * 2 + 1) * WS_STRIDE;
  const float m0 = b0[0], Z0 = b0[1];
  const float m1 = b1[0], Z1 = b1[1];
  const float mm = fmaxf(m0, m1);
  const float w0 = __expf(m0 - mm);
  const float w1 = __expf(m1 - mm);
  const float Zi = 1.f / (Z0 * w0 + Z1 * w1);

  pooled_sm[t] = (b0[2 + t] * w0 + b1[2 + t] * w1) * Zi;
  __syncthreads();

  float s = 0.f;
#pragma unroll
  for (int i = 0; i < 4; ++i) {
    const int h = i * 64 + lane;
    s = fmaf(pooled_sm[h], MetaW[(size_t)wave * NH + h], s);
  }
#pragma unroll
  for (int off = 32; off > 0; off >>= 1)
    s += __shfl_down(s, off);
  if (lane == 0)
    out[b * 4 + wave] = s + Metab[wave];
}

extern "C" void kernel_launch(void* const* d_in, const int* in_sizes, int n_in,
                              void* d_out, int out_size, void* d_ws, size_t ws_size,
                              hipStream_t stream) {
  const float* mem   = (const float*)d_in[0];
  const float* lastm = (const float*)d_in[1];
  const float* U     = (const float*)d_in[2];
  const float* W     = (const float*)d_in[3];
  const float* V     = (const float*)d_in[4];
  const float* MetaW = (const float*)d_in[5];
  const float* Metab = (const float*)d_in[6];
  float* out = (float*)d_out;
  float* ws  = (float*)d_ws;

  float* part = ws + OFF_PART;

  if (ws_size >= (size_t)WS_FLOATS_PRE * sizeof(float)) {
    float*    l_ws = ws + OFF_L;
    _Float16* Uswz = (_Float16*)(ws + OFF_UB);
    hipLaunchKernelGGL(precompute, dim3(NB + 32), dim3(256), 0, stream,
                       lastm, W, U, l_ws, Uswz);
    hipLaunchKernelGGL(fused_meta_attn_part<true>, dim3(NPART), dim3(512), 0, stream,
                       mem, lastm, U, W, V, l_ws, Uswz, part);
  } else {
    hipLaunchKernelGGL(fused_meta_attn_part<false>, dim3(NPART), dim3(512), 0, stream,
                       mem, lastm, U, W, V, (const float*)nullptr, (const _Float16*)nullptr, part);
  }
  hipLaunchKernelGGL(merge_project, dim3(NB), dim3(256), 0, stream,
                     part, MetaW, Metab, out);
}